// Round 8
// baseline (262.450 us; speedup 1.0000x reference)
//
#include <hip/hip_runtime.h>

typedef unsigned short u16;
typedef __bf16 bf16x8 __attribute__((ext_vector_type(8)));
typedef unsigned short u16x8 __attribute__((ext_vector_type(8)));
typedef float f32x4 __attribute__((ext_vector_type(4)));

// XOR swizzle key for [row][64] bf16 LDS tiles, 8-elem (16B) chunk granularity.
#define KEY(r) ((((r) ^ ((r) >> 3)) & 7) << 3)

static __device__ __forceinline__ u16 f2b(float f) {
  union { float f; unsigned u; } x; x.f = f;
  unsigned r = x.u + 0x7FFFu + ((x.u >> 16) & 1u);  // RNE
  return (u16)(r >> 16);
}

static __device__ __forceinline__ bf16x8 ld_frag(const u16* p) {
  union { u16x8 s; bf16x8 b; } u;
  u.s = *reinterpret_cast<const u16x8*>(p);
  return u.b;
}

// ---------------- f32 -> bf16 convert (vectorized x4) ----------------
__global__ __launch_bounds__(256) void cvt_f32_bf16(const float* __restrict__ in,
                                                    u16* __restrict__ out, int n4) {
  int i = blockIdx.x * 256 + threadIdx.x;
  if (i >= n4) return;
  float4 v = reinterpret_cast<const float4*>(in)[i];
  ushort4 o;
  o.x = f2b(v.x); o.y = f2b(v.y); o.z = f2b(v.z); o.w = f2b(v.w);
  reinterpret_cast<ushort4*>(out)[i] = o;
}

// ---------------- GEMM body: 128xBN tile, BK=64 -----------------------------
// 4 waves 2x2. global_load_lds w16, pre-swizzled source + swizzled ds_read.
template <bool OUT_BF16, int BN>   // BN in {64,128}
static __device__ __forceinline__ void gemm_body(
    const u16* __restrict__ A, const u16* __restrict__ Bt,
    const float* __restrict__ bias, void* __restrict__ outp,
    int N, int K, int row0, int col0, float scale) {
  constexpr int NF = BN / 32;        // n-frags per wave (4 or 2)
  __shared__ alignas(16) u16 As[128 * 64];
  __shared__ alignas(16) u16 Bs[BN * 64];
  const int tid = threadIdx.x, wid = tid >> 6, lane = tid & 63;
  const int wr = wid >> 1, wc = wid & 1;
  const int lr = lane >> 3;         // 0..7
  const int lc = (lane & 7) * 8;    // 0..56
  const int frow = lane & 15, fk = (lane >> 4) * 8;
  f32x4 acc[4][NF] = {};

  for (int k0 = 0; k0 < K; k0 += 64) {
    __syncthreads();
#pragma unroll
    for (int t = 0; t < 4; ++t) {
      const int r = wid * 32 + t * 8 + lr;
      __builtin_amdgcn_global_load_lds(
          (const __attribute__((address_space(1))) unsigned int*)(
              A + (size_t)(row0 + r) * K + k0 + (lc ^ KEY(r))),
          (__attribute__((address_space(3))) unsigned int*)(As + (wid * 32 + t * 8) * 64),
          16, 0, 0);
    }
#pragma unroll
    for (int t = 0; t < NF; ++t) {
      const int r = wid * (BN / 4) + t * 8 + lr;
      __builtin_amdgcn_global_load_lds(
          (const __attribute__((address_space(1))) unsigned int*)(
              Bt + (size_t)(col0 + r) * K + k0 + (lc ^ KEY(r))),
          (__attribute__((address_space(3))) unsigned int*)(Bs + (wid * (BN / 4) + t * 8) * 64),
          16, 0, 0);
    }
    __syncthreads();
#pragma unroll
    for (int ks = 0; ks < 2; ++ks) {
      bf16x8 a[4], b[NF];
#pragma unroll
      for (int m = 0; m < 4; ++m) {
        const int r = wr * 64 + m * 16 + frow;
        a[m] = ld_frag(&As[r * 64 + ((ks * 32 + fk) ^ KEY(r))]);
      }
#pragma unroll
      for (int n = 0; n < NF; ++n) {
        const int r = wc * (BN / 2) + n * 16 + frow;
        b[n] = ld_frag(&Bs[r * 64 + ((ks * 32 + fk) ^ KEY(r))]);
      }
#pragma unroll
      for (int m = 0; m < 4; ++m)
#pragma unroll
        for (int n = 0; n < NF; ++n)
          acc[m][n] = __builtin_amdgcn_mfma_f32_16x16x32_bf16(a[m], b[n], acc[m][n], 0, 0, 0);
    }
  }
  const int colL = lane & 15, rb = (lane >> 4) * 4;
#pragma unroll
  for (int n = 0; n < NF; ++n) {
    const int gc = col0 + wc * (BN / 2) + n * 16 + colL;
    const float bv = bias[gc];
#pragma unroll
    for (int m = 0; m < 4; ++m)
#pragma unroll
      for (int r = 0; r < 4; ++r) {
        const int gr = row0 + wr * 64 + m * 16 + rb + r;
        const float v = (acc[m][n][r] + bv) * scale;
        if constexpr (OUT_BF16)
          reinterpret_cast<u16*>(outp)[(size_t)gr * N + gc] = f2b(v);
        else
          reinterpret_cast<float*>(outp)[(size_t)gr * N + gc] = v;
      }
  }
}

// Fused Q + KV projection (shared A panel; branch is block-uniform).
__global__ __launch_bounds__(256) void gemm_qkv(
    const u16* __restrict__ xb, const u16* __restrict__ wqb,
    const u16* __restrict__ wkvb, const float* __restrict__ bq,
    const float* __restrict__ bkv, u16* __restrict__ qb, u16* __restrict__ kvb) {
  const int row0 = blockIdx.x * 128;
  const int by = blockIdx.y;
  const u16* Bt; const float* bias; u16* out; int N, col0; float scale;
  if (by < 8) { Bt = wqb;  bias = bq;  out = qb;  N = 1024; col0 = by * 128;      scale = 0.125f; }
  else        { Bt = wkvb; bias = bkv; out = kvb; N = 2048; col0 = (by - 8) * 128; scale = 1.0f; }
  gemm_body<true, 128>(xb, Bt, bias, out, N, 1024, row0, col0, scale);
}

// O-projection: BN=64 tiles -> 512 blocks (2/CU) instead of 256 (1/CU).
__global__ __launch_bounds__(256) void gemm_o(
    const u16* __restrict__ yb, const u16* __restrict__ wob,
    const float* __restrict__ bo, float* __restrict__ out) {
  gemm_body<false, 64>(yb, wob, bo, out, 1024, 1024, blockIdx.x * 128, blockIdx.y * 64, 1.0f);
}

// ---------------- Flash attention with ALiBi + causal ----------------
// grid: (B*H, T/128), qt = gridDim.y-1-blockIdx.y (LPT). block: 256 (4 waves),
// wave w owns q rows [qBase+32w, +32) as 2 m-frags. K/V reg-prefetched; all
// LDS tiles pitch-64 XOR-swizzled (conflict-free b128 frag reads).
__global__ __launch_bounds__(256) void attn_kernel(
    const u16* __restrict__ qb,   // [B*T,1024] bf16, pre-scaled by 1/8
    const u16* __restrict__ kvb,  // [B*T,2048] bf16 (k: h*64, v: 1024+h*64)
    u16* __restrict__ yb,         // [B*T,1024] bf16
    int T) {
  const int C = 1024;
  const int bh = blockIdx.x;
  const int qt = gridDim.y - 1 - blockIdx.y;
  const int b = bh >> 4, h = bh & 15;
  const float slope = (float)(h + 1) * 0.0625f;
  const int tid = threadIdx.x, wid = tid >> 6, lane = tid & 63;
  const int qBase = qt * 128;

  __shared__ alignas(16) u16 Ks[64 * 64];      // K[k][d ^ KEY(k)]
  __shared__ alignas(16) u16 Vt[64 * 64];      // V^T: Vt[d][k ^ KEY(d)]
  __shared__ alignas(16) u16 Ps[4][32 * 64];   // P[q][c ^ PK(q)] per wave

  const int frow = lane & 15, fk = (lane >> 4) * 8;
  const int col = lane & 15, rb = (lane >> 4) * 4;
  const int pk = ((lane >> 4) & 3) << 3;       // == PK(m*16+rb+r) for r<4

  // Q fragments (loop-invariant): 2 m-frags per wave
  bf16x8 aq[2][2];
#pragma unroll
  for (int m = 0; m < 2; ++m) {
    const int q_row = qBase + wid * 32 + m * 16 + frow;
    const u16* qp = qb + (size_t)(b * T + q_row) * C + h * 64;
    aq[m][0] = ld_frag(qp + fk);
    aq[m][1] = ld_frag(qp + 32 + fk);
  }

  float mrow[2][4], lrow[2][4];
  f32x4 accO[2][4] = {};
#pragma unroll
  for (int m = 0; m < 2; ++m)
#pragma unroll
    for (int r = 0; r < 4; ++r) { mrow[m][r] = -1e30f; lrow[m][r] = 0.f; }

  const int st_r = tid >> 3;        // 0..31
  const int st_c = (tid & 7) * 8;   // 0..56
  const int vkj = tid & 7;          // (d>>3) for d = st_c+j

  const int nt = 2 * qt + 2;        // k-tiles covering [0, qBase+128)

  int4 kreg[2], vreg[2];
#pragma unroll
  for (int t = 0; t < 2; ++t) {  // prologue: tile 0
    const int r = st_r + 32 * t;
    const size_t g = (size_t)(b * T + r) * 2048 + h * 64 + st_c;
    kreg[t] = *reinterpret_cast<const int4*>(&kvb[g]);
    vreg[t] = *reinterpret_cast<const int4*>(&kvb[g + 1024]);
  }

  for (int kt = 0; kt < nt; ++kt) {
    const int kBase = kt * 64;
    // staged regs -> LDS (K rows, V transposed)
#pragma unroll
    for (int t = 0; t < 2; ++t) {
      const int r = st_r + 32 * t;
      *reinterpret_cast<int4*>(&Ks[r * 64 + (st_c ^ KEY(r))]) = kreg[t];
      const u16* pv = reinterpret_cast<const u16*>(&vreg[t]);
#pragma unroll
      for (int j = 0; j < 8; ++j) {
        const int d = st_c + j;
        Vt[d * 64 + (r ^ (((j ^ vkj) & 7) << 3))] = pv[j];  // == r ^ KEY(d)
      }
    }
    __syncthreads();
    // prefetch next tile into regs (latency hides under compute)
    if (kt + 1 < nt) {
#pragma unroll
      for (int t = 0; t < 2; ++t) {
        const int r = st_r + 32 * t;
        const size_t g = (size_t)(b * T + kBase + 64 + r) * 2048 + h * 64 + st_c;
        kreg[t] = *reinterpret_cast<const int4*>(&kvb[g]);
        vreg[t] = *reinterpret_cast<const int4*>(&kvb[g + 1024]);
      }
    }

    // S = Q K^T  (per wave: 32 q-rows x 64 keys)
    f32x4 accS[2][4] = {};
    __builtin_amdgcn_s_setprio(1);
#pragma unroll
    for (int n = 0; n < 4; ++n) {
      const int r = n * 16 + frow;
      bf16x8 bk0 = ld_frag(&Ks[r * 64 + (fk ^ KEY(r))]);
      bf16x8 bk1 = ld_frag(&Ks[r * 64 + ((32 + fk) ^ KEY(r))]);
#pragma unroll
      for (int m = 0; m < 2; ++m) {
        accS[m][n] = __builtin_amdgcn_mfma_f32_16x16x32_bf16(aq[m][0], bk0, accS[m][n], 0, 0, 0);
        accS[m][n] = __builtin_amdgcn_mfma_f32_16x16x32_bf16(aq[m][1], bk1, accS[m][n], 0, 0, 0);
      }
    }
    __builtin_amdgcn_s_setprio(0);

    // online softmax; ALiBi bias = slope*kg (per-row -slope*qg shift cancels)
    float bn[4]; int kg[4];
#pragma unroll
    for (int n = 0; n < 4; ++n) { kg[n] = kBase + n * 16 + col; bn[n] = slope * (float)kg[n]; }
#pragma unroll
    for (int m = 0; m < 2; ++m)
#pragma unroll
      for (int r = 0; r < 4; ++r) {
        const int qg = qBase + wid * 32 + m * 16 + rb + r;
        float s[4];
        float tmax = -1e30f;
#pragma unroll
        for (int n = 0; n < 4; ++n) {
          float v = accS[m][n][r] + bn[n];
          if (kg[n] > qg) v = -1e30f;
          s[n] = v;
          tmax = fmaxf(tmax, v);
        }
        tmax = fmaxf(tmax, __shfl_xor(tmax, 1));
        tmax = fmaxf(tmax, __shfl_xor(tmax, 2));
        tmax = fmaxf(tmax, __shfl_xor(tmax, 4));
        tmax = fmaxf(tmax, __shfl_xor(tmax, 8));
        const float newm = fmaxf(mrow[m][r], tmax);
        const float corr = __expf(mrow[m][r] - newm);
        mrow[m][r] = newm;
        float psum = 0.f;
#pragma unroll
        for (int n = 0; n < 4; ++n) {
          const float p = __expf(s[n] - newm);
          psum += p;
          Ps[wid][(m * 16 + rb + r) * 64 + ((n * 16 + col) ^ pk)] = f2b(p);
        }
        psum += __shfl_xor(psum, 1);
        psum += __shfl_xor(psum, 2);
        psum += __shfl_xor(psum, 4);
        psum += __shfl_xor(psum, 8);
        lrow[m][r] = lrow[m][r] * corr + psum;
#pragma unroll
        for (int n = 0; n < 4; ++n) accO[m][n][r] *= corr;
      }
    // no barrier: Ps is wave-private; within-wave ds ordering suffices

    // O += P @ V
    __builtin_amdgcn_s_setprio(1);
#pragma unroll
    for (int ks = 0; ks < 2; ++ks) {
      const int pkr = ((frow >> 2) & 3) << 3;  // PK(frow)
      bf16x8 ap[2];
#pragma unroll
      for (int m = 0; m < 2; ++m)
        ap[m] = ld_frag(&Ps[wid][(m * 16 + frow) * 64 + ((ks * 32 + fk) ^ pkr)]);
#pragma unroll
      for (int n = 0; n < 4; ++n) {
        const int d = n * 16 + frow;
        bf16x8 bv = ld_frag(&Vt[d * 64 + ((ks * 32 + fk) ^ KEY(d))]);
#pragma unroll
        for (int m = 0; m < 2; ++m)
          accO[m][n] = __builtin_amdgcn_mfma_f32_16x16x32_bf16(ap[m], bv, accO[m][n], 0, 0, 0);
      }
    }
    __builtin_amdgcn_s_setprio(0);
    __syncthreads();  // all reads done before next tile's LDS writes
  }

  // normalize + store
#pragma unroll
  for (int m = 0; m < 2; ++m)
#pragma unroll
    for (int r = 0; r < 4; ++r) {
      const float inv = 1.0f / lrow[m][r];
      const int qg = qBase + wid * 32 + m * 16 + rb + r;
      u16* yrow = yb + (size_t)(b * T + qg) * C + h * 64;
#pragma unroll
      for (int n = 0; n < 4; ++n) yrow[n * 16 + col] = f2b(accO[m][n][r] * inv);
    }
}

extern "C" void kernel_launch(void* const* d_in, const int* in_sizes, int n_in,
                              void* d_out, int out_size, void* d_ws, size_t ws_size,
                              hipStream_t stream) {
  const float* x   = (const float*)d_in[0];
  // d_in[1] = freqs_cis (unused under ALiBi)
  const float* Wq  = (const float*)d_in[2];
  const float* bq  = (const float*)d_in[3];
  const float* Wkv = (const float*)d_in[4];
  const float* bkv = (const float*)d_in[5];
  const float* Wo  = (const float*)d_in[6];
  const float* bo  = (const float*)d_in[7];
  float* out = (float*)d_out;

  const int B = 2, T = 2048, C = 1024;
  const int M = B * T;  // 4096

  char* ws = (char*)d_ws;
  u16* xb   = (u16*)(ws + 0);          // 4096x1024  (8 MiB)
  u16* wqb  = (u16*)(ws + 8388608);    // 1024x1024  (2 MiB)
  u16* wkvb = (u16*)(ws + 10485760);   // 2048x1024  (4 MiB)
  u16* wob  = (u16*)(ws + 14680064);   // 1024x1024  (2 MiB)
  u16* qb   = (u16*)(ws + 16777216);   // 4096x1024  (8 MiB)
  u16* kvb  = (u16*)(ws + 25165824);   // 4096x2048  (16 MiB)
  u16* yb   = (u16*)(ws + 41943040);   // 4096x1024  (8 MiB)

  cvt_f32_bf16<<<(M * C / 4 + 255) / 256, 256, 0, stream>>>(x, xb, M * C / 4);
  cvt_f32_bf16<<<(C * C / 4 + 255) / 256, 256, 0, stream>>>(Wq, wqb, C * C / 4);
  cvt_f32_bf16<<<(2 * C * C / 4 + 255) / 256, 256, 0, stream>>>(Wkv, wkvb, 2 * C * C / 4);
  cvt_f32_bf16<<<(C * C / 4 + 255) / 256, 256, 0, stream>>>(Wo, wob, C * C / 4);

  // fused: q = (x@Wq^T + bq)*0.125 ; kv = x@Wkv^T + bkv
  gemm_qkv<<<dim3(M / 128, 8 + 16), 256, 0, stream>>>(xb, wqb, wkvb, bq, bkv, qb, kvb);
  // flash attention (grid: bh x qtile128, reversed for LPT balance)
  attn_kernel<<<dim3(B * 16, T / 128), 256, 0, stream>>>(qb, kvb, yb, T);
  // out = y @ Wo^T + bo  (f32 out)
  gemm_o<<<dim3(M / 128, C / 64), 256, 0, stream>>>(yb, wob, bo, out);
}

// Round 9
// 243.178 us; speedup vs baseline: 1.0793x; 1.0793x over previous
//
#include <hip/hip_runtime.h>

typedef unsigned short u16;
typedef __bf16 bf16x8 __attribute__((ext_vector_type(8)));
typedef unsigned short u16x8 __attribute__((ext_vector_type(8)));
typedef float f32x4 __attribute__((ext_vector_type(4)));

// XOR swizzle key for [row][64] bf16 LDS tiles (GEMM), 16B chunk granularity.
#define KEY(r) ((((r) ^ ((r) >> 3)) & 7) << 3)
// attn layouts: pitch-72 (144B) rows, V^T k-swizzle keyed on d>>3 (round-3 proven)
#define GP 72
#define VKEY(d) ((((d) >> 3) & 7) << 3)

static __device__ __forceinline__ u16 f2b(float f) {
  union { float f; unsigned u; } x; x.f = f;
  unsigned r = x.u + 0x7FFFu + ((x.u >> 16) & 1u);  // RNE
  return (u16)(r >> 16);
}

static __device__ __forceinline__ float b2f(u16 s) {
  union { unsigned u; float f; } z; z.u = (unsigned)s << 16; return z.f;
}

static __device__ __forceinline__ bf16x8 ld_frag(const u16* p) {
  union { u16x8 s; bf16x8 b; } u;
  u.s = *reinterpret_cast<const u16x8*>(p);
  return u.b;
}

// ---------------- f32 -> bf16 convert (vectorized x4) ----------------
__global__ __launch_bounds__(256) void cvt_f32_bf16(const float* __restrict__ in,
                                                    u16* __restrict__ out, int n4) {
  int i = blockIdx.x * 256 + threadIdx.x;
  if (i >= n4) return;
  float4 v = reinterpret_cast<const float4*>(in)[i];
  ushort4 o;
  o.x = f2b(v.x); o.y = f2b(v.y); o.z = f2b(v.z); o.w = f2b(v.w);
  reinterpret_cast<ushort4*>(out)[i] = o;
}

// ---------------- GEMM body: 128xBN tile, BK=64 (unchanged from r8) ---------
template <bool OUT_BF16, int BN>   // BN in {64,128}
static __device__ __forceinline__ void gemm_body(
    const u16* __restrict__ A, const u16* __restrict__ Bt,
    const float* __restrict__ bias, void* __restrict__ outp,
    int N, int K, int row0, int col0, float scale) {
  constexpr int NF = BN / 32;
  __shared__ alignas(16) u16 As[128 * 64];
  __shared__ alignas(16) u16 Bs[BN * 64];
  const int tid = threadIdx.x, wid = tid >> 6, lane = tid & 63;
  const int wr = wid >> 1, wc = wid & 1;
  const int lr = lane >> 3;
  const int lc = (lane & 7) * 8;
  const int frow = lane & 15, fk = (lane >> 4) * 8;
  f32x4 acc[4][NF] = {};

  for (int k0 = 0; k0 < K; k0 += 64) {
    __syncthreads();
#pragma unroll
    for (int t = 0; t < 4; ++t) {
      const int r = wid * 32 + t * 8 + lr;
      __builtin_amdgcn_global_load_lds(
          (const __attribute__((address_space(1))) unsigned int*)(
              A + (size_t)(row0 + r) * K + k0 + (lc ^ KEY(r))),
          (__attribute__((address_space(3))) unsigned int*)(As + (wid * 32 + t * 8) * 64),
          16, 0, 0);
    }
#pragma unroll
    for (int t = 0; t < NF; ++t) {
      const int r = wid * (BN / 4) + t * 8 + lr;
      __builtin_amdgcn_global_load_lds(
          (const __attribute__((address_space(1))) unsigned int*)(
              Bt + (size_t)(col0 + r) * K + k0 + (lc ^ KEY(r))),
          (__attribute__((address_space(3))) unsigned int*)(Bs + (wid * (BN / 4) + t * 8) * 64),
          16, 0, 0);
    }
    __syncthreads();
#pragma unroll
    for (int ks = 0; ks < 2; ++ks) {
      bf16x8 a[4], b[NF];
#pragma unroll
      for (int m = 0; m < 4; ++m) {
        const int r = wr * 64 + m * 16 + frow;
        a[m] = ld_frag(&As[r * 64 + ((ks * 32 + fk) ^ KEY(r))]);
      }
#pragma unroll
      for (int n = 0; n < NF; ++n) {
        const int r = wc * (BN / 2) + n * 16 + frow;
        b[n] = ld_frag(&Bs[r * 64 + ((ks * 32 + fk) ^ KEY(r))]);
      }
#pragma unroll
      for (int m = 0; m < 4; ++m)
#pragma unroll
        for (int n = 0; n < NF; ++n)
          acc[m][n] = __builtin_amdgcn_mfma_f32_16x16x32_bf16(a[m], b[n], acc[m][n], 0, 0, 0);
    }
  }
  const int colL = lane & 15, rb = (lane >> 4) * 4;
#pragma unroll
  for (int n = 0; n < NF; ++n) {
    const int gc = col0 + wc * (BN / 2) + n * 16 + colL;
    const float bv = bias[gc];
#pragma unroll
    for (int m = 0; m < 4; ++m)
#pragma unroll
      for (int r = 0; r < 4; ++r) {
        const int gr = row0 + wr * 64 + m * 16 + rb + r;
        const float v = (acc[m][n][r] + bv) * scale;
        if constexpr (OUT_BF16)
          reinterpret_cast<u16*>(outp)[(size_t)gr * N + gc] = f2b(v);
        else
          reinterpret_cast<float*>(outp)[(size_t)gr * N + gc] = v;
      }
  }
}

__global__ __launch_bounds__(256) void gemm_qkv(
    const u16* __restrict__ xb, const u16* __restrict__ wqb,
    const u16* __restrict__ wkvb, const float* __restrict__ bq,
    const float* __restrict__ bkv, u16* __restrict__ qb, u16* __restrict__ kvb) {
  const int row0 = blockIdx.x * 128;
  const int by = blockIdx.y;
  const u16* Bt; const float* bias; u16* out; int N, col0; float scale;
  if (by < 8) { Bt = wqb;  bias = bq;  out = qb;  N = 1024; col0 = by * 128;      scale = 0.125f; }
  else        { Bt = wkvb; bias = bkv; out = kvb; N = 2048; col0 = (by - 8) * 128; scale = 1.0f; }
  gemm_body<true, 128>(xb, Bt, bias, out, N, 1024, row0, col0, scale);
}

__global__ __launch_bounds__(256) void gemm_o(
    const u16* __restrict__ yb, const u16* __restrict__ wob,
    const float* __restrict__ bo, float* __restrict__ out) {
  gemm_body<false, 64>(yb, wob, bo, out, 1024, 1024, blockIdx.x * 128, blockIdx.y * 64, 1.0f);
}

// ---------------- Flash attention, split-K + ALiBi + causal -----------------
// Round-3 per-tile body (proven 90.7us). Work decomposition: grid (B*H, 48).
// y<32: qt = 31-(y>>1) in [16,31], chunk = y&1 -> k-tiles split in half,
//       write UNNORMALIZED partial (O bf16 + m,l f32) to scratch record.
// y>=32: qt = 47-y in [0,15], full range, write y directly (normalized).
// Record: 8704 B = O[64][64] bf16 (8192) + m[64] f32 (256) + l[64] f32 (256).
__global__ __launch_bounds__(256) void attn_split(
    const u16* __restrict__ qb,   // [B*T,1024] bf16, pre-scaled by 1/8
    const u16* __restrict__ kvb,  // [B*T,2048] bf16 (k: h*64, v: 1024+h*64)
    u16* __restrict__ yb,         // [B*T,1024] bf16
    char* __restrict__ part,      // split-K partial records
    int T) {
  const int C = 1024;
  const int bh = blockIdx.x;
  const int b = bh >> 4, h = bh & 15;
  const float slope = (float)(h + 1) * 0.0625f;
  const int tid = threadIdx.x, wid = tid >> 6, lane = tid & 63;

  const int y = blockIdx.y;
  int qt, t0, t1, pidx; bool direct;
  if (y < 32) {
    qt = 31 - (y >> 1);
    const int c = y & 1, nt = qt + 1, half = (nt + 1) >> 1;
    t0 = c ? half : 0; t1 = c ? nt : half;
    direct = false;
    pidx = ((bh << 4) + (qt - 16)) * 2 + c;
  } else {
    qt = 47 - y; t0 = 0; t1 = qt + 1; direct = true; pidx = 0;
  }
  const int qBase = qt * 64;

  __shared__ alignas(16) u16 Ks[64 * GP];   // K[k][d]
  __shared__ alignas(16) u16 Vt[64 * GP];   // V^T: Vt[d][k ^ VKEY(d)]
  __shared__ alignas(16) u16 Ps[4][16 * GP];

  const int frow = lane & 15, fk = (lane >> 4) * 8;
  const int col = lane & 15, rb = (lane >> 4) * 4;

  // Q fragments (loop-invariant)
  const int q_row = qBase + wid * 16 + frow;
  const u16* qp = qb + (size_t)(b * T + q_row) * C + h * 64;
  const bf16x8 aq0 = ld_frag(qp + fk);
  const bf16x8 aq1 = ld_frag(qp + 32 + fk);

  float mrow[4] = {-1e30f, -1e30f, -1e30f, -1e30f};
  float lrow[4] = {0.f, 0.f, 0.f, 0.f};
  f32x4 accO[4] = {};

  const int sr = tid >> 3;        // 0..31
  const int sc = (tid & 7) * 8;   // 0..56

  for (int kt = t0; kt < t1; ++kt) {
    const int kBase = kt * 64;
    __syncthreads();  // previous iteration's reads of Ks/Vt done
    {  // stage K rows + V transposed
      const size_t g0 = (size_t)(b * T + kBase + sr) * 2048 + h * 64 + sc;
      const size_t g1 = (size_t)(b * T + kBase + sr + 32) * 2048 + h * 64 + sc;
      *reinterpret_cast<int4*>(&Ks[sr * GP + sc]) = *reinterpret_cast<const int4*>(&kvb[g0]);
      *reinterpret_cast<int4*>(&Ks[(sr + 32) * GP + sc]) = *reinterpret_cast<const int4*>(&kvb[g1]);
      int4 v0 = *reinterpret_cast<const int4*>(&kvb[g0 + 1024]);
      int4 v1 = *reinterpret_cast<const int4*>(&kvb[g1 + 1024]);
      const u16* p0 = reinterpret_cast<const u16*>(&v0);
      const u16* p1 = reinterpret_cast<const u16*>(&v1);
      const int kx = VKEY(sc);  // d>>3 == sc>>3 for all 8 elems
#pragma unroll
      for (int j = 0; j < 8; ++j) {
        const int d = sc + j;
        Vt[d * GP + (sr ^ kx)] = p0[j];
        Vt[d * GP + ((sr + 32) ^ kx)] = p1[j];
      }
    }
    __syncthreads();

    // S = Q K^T (per wave: 16 q-rows x 64 keys)
    f32x4 accS[4] = {};
#pragma unroll
    for (int n = 0; n < 4; ++n) {
      bf16x8 bk0 = ld_frag(&Ks[(n * 16 + frow) * GP + fk]);
      accS[n] = __builtin_amdgcn_mfma_f32_16x16x32_bf16(aq0, bk0, accS[n], 0, 0, 0);
      bf16x8 bk1 = ld_frag(&Ks[(n * 16 + frow) * GP + 32 + fk]);
      accS[n] = __builtin_amdgcn_mfma_f32_16x16x32_bf16(aq1, bk1, accS[n], 0, 0, 0);
    }

    // online softmax per owned row r
#pragma unroll
    for (int r = 0; r < 4; ++r) {
      const int qg = qBase + wid * 16 + rb + r;
      float s[4];
      float tmax = -1e30f;
#pragma unroll
      for (int n = 0; n < 4; ++n) {
        const int kg = kBase + n * 16 + col;
        float v = accS[n][r] + slope * (float)(kg - qg);
        if (kg > qg) v = -1e30f;
        s[n] = v;
        tmax = fmaxf(tmax, v);
      }
      tmax = fmaxf(tmax, __shfl_xor(tmax, 1));
      tmax = fmaxf(tmax, __shfl_xor(tmax, 2));
      tmax = fmaxf(tmax, __shfl_xor(tmax, 4));
      tmax = fmaxf(tmax, __shfl_xor(tmax, 8));
      const float newm = fmaxf(mrow[r], tmax);
      const float corr = __expf(mrow[r] - newm);
      mrow[r] = newm;
      float psum = 0.f;
#pragma unroll
      for (int n = 0; n < 4; ++n) {
        const float p = __expf(s[n] - newm);
        psum += p;
        Ps[wid][(rb + r) * GP + n * 16 + col] = f2b(p);
      }
      psum += __shfl_xor(psum, 1);
      psum += __shfl_xor(psum, 2);
      psum += __shfl_xor(psum, 4);
      psum += __shfl_xor(psum, 8);
      lrow[r] = lrow[r] * corr + psum;
#pragma unroll
      for (int n = 0; n < 4; ++n) accO[n][r] *= corr;
    }
    // no barrier: Ps is wave-private; within-wave ds ordering suffices

    // O += P @ V
#pragma unroll
    for (int ks = 0; ks < 2; ++ks) {
      bf16x8 ap = ld_frag(&Ps[wid][frow * GP + ks * 32 + fk]);
#pragma unroll
      for (int n = 0; n < 4; ++n) {
        const int d = n * 16 + frow;
        bf16x8 bv = ld_frag(&Vt[d * GP + ((ks * 32 + fk) ^ VKEY(d))]);
        accO[n] = __builtin_amdgcn_mfma_f32_16x16x32_bf16(ap, bv, accO[n], 0, 0, 0);
      }
    }
  }

  if (direct) {
    // normalize + store y
#pragma unroll
    for (int r = 0; r < 4; ++r) {
      const float inv = 1.0f / lrow[r];
      const int qg = qBase + wid * 16 + rb + r;
      u16* yrow = yb + (size_t)(b * T + qg) * C + h * 64;
#pragma unroll
      for (int n = 0; n < 4; ++n) yrow[n * 16 + col] = f2b(accO[n][r] * inv);
    }
  } else {
    // store unnormalized partial record
    u16* Orec = (u16*)(part + (size_t)pidx * 8704);
    float* mrec = (float*)(part + (size_t)pidx * 8704 + 8192);  // m[64], then l[64]
#pragma unroll
    for (int r = 0; r < 4; ++r) {
      const int row = wid * 16 + rb + r;
#pragma unroll
      for (int n = 0; n < 4; ++n)
        Orec[row * 64 + n * 16 + col] = f2b(accO[n][r]);
      if (col == 0) { mrec[row] = mrow[r]; mrec[64 + row] = lrow[r]; }
    }
  }
}

// Combine the two partials for qt in [16,31]. grid (B*H, 16), 256 thr.
__global__ __launch_bounds__(256) void attn_combine(
    const char* __restrict__ part, u16* __restrict__ yb, int T) {
  const int C = 1024;
  const int bh = blockIdx.x, b = bh >> 4, h = bh & 15;
  const int qt = 16 + blockIdx.y;
  const int tid = threadIdx.x;
  const int row = tid >> 2;            // 0..63
  const int d0 = (tid & 3) * 16;       // 0,16,32,48
  const size_t base = (size_t)(((bh << 4) + (qt - 16)) * 2) * 8704;
  const char* r0 = part + base;
  const char* r1 = part + base + 8704;
  const float m0 = ((const float*)(r0 + 8192))[row];
  const float l0 = ((const float*)(r0 + 8192))[64 + row];
  const float m1 = ((const float*)(r1 + 8192))[row];
  const float l1 = ((const float*)(r1 + 8192))[64 + row];
  const float M = fmaxf(m0, m1);
  const float w0 = __expf(m0 - M), w1 = __expf(m1 - M);
  const float inv = 1.0f / (l0 * w0 + l1 * w1);
  const u16* o0 = (const u16*)r0 + row * 64 + d0;
  const u16* o1 = (const u16*)r1 + row * 64 + d0;
  alignas(16) u16 outv[16];
#pragma unroll
  for (int j = 0; j < 16; ++j)
    outv[j] = f2b((b2f(o0[j]) * w0 + b2f(o1[j]) * w1) * inv);
  u16* yrow = yb + (size_t)(b * T + qt * 64 + row) * C + h * 64 + d0;
  *reinterpret_cast<int4*>(yrow) = *reinterpret_cast<const int4*>(outv);
  *reinterpret_cast<int4*>(yrow + 8) = *reinterpret_cast<const int4*>(outv + 8);
}

extern "C" void kernel_launch(void* const* d_in, const int* in_sizes, int n_in,
                              void* d_out, int out_size, void* d_ws, size_t ws_size,
                              hipStream_t stream) {
  const float* x   = (const float*)d_in[0];
  // d_in[1] = freqs_cis (unused under ALiBi)
  const float* Wq  = (const float*)d_in[2];
  const float* bq  = (const float*)d_in[3];
  const float* Wkv = (const float*)d_in[4];
  const float* bkv = (const float*)d_in[5];
  const float* Wo  = (const float*)d_in[6];
  const float* bo  = (const float*)d_in[7];
  float* out = (float*)d_out;

  const int B = 2, T = 2048, C = 1024;
  const int M = B * T;  // 4096

  char* ws = (char*)d_ws;
  u16* xb   = (u16*)(ws + 0);          // 4096x1024  (8 MiB)   } dead after gemm_qkv;
  u16* wqb  = (u16*)(ws + 8388608);    // 1024x1024  (2 MiB)   } reused as split-K
  u16* wkvb = (u16*)(ws + 10485760);   // 2048x1024  (4 MiB)   } partial scratch (8.9 MiB)
  u16* wob  = (u16*)(ws + 14680064);   // 1024x1024  (2 MiB) -- live until gemm_o
  u16* qb   = (u16*)(ws + 16777216);   // 4096x1024  (8 MiB)
  u16* kvb  = (u16*)(ws + 25165824);   // 4096x2048  (16 MiB)
  u16* yb   = (u16*)(ws + 41943040);   // 4096x1024  (8 MiB)
  char* part = ws;                     // 1024 records x 8704 B, aliases xb/wqb

  cvt_f32_bf16<<<(M * C / 4 + 255) / 256, 256, 0, stream>>>(x, xb, M * C / 4);
  cvt_f32_bf16<<<(C * C / 4 + 255) / 256, 256, 0, stream>>>(Wq, wqb, C * C / 4);
  cvt_f32_bf16<<<(2 * C * C / 4 + 255) / 256, 256, 0, stream>>>(Wkv, wkvb, 2 * C * C / 4);
  cvt_f32_bf16<<<(C * C / 4 + 255) / 256, 256, 0, stream>>>(Wo, wob, C * C / 4);

  // fused: q = (x@Wq^T + bq)*0.125 ; kv = x@Wkv^T + bkv
  gemm_qkv<<<dim3(M / 128, 8 + 16), 256, 0, stream>>>(xb, wqb, wkvb, bq, bkv, qb, kvb);
  // split-K flash attention (48 blocks per bh: 32 split chunks LPT-first, 16 direct)
  attn_split<<<dim3(B * 16, 48), 256, 0, stream>>>(qb, kvb, yb, part, T);
  attn_combine<<<dim3(B * 16, 16), 256, 0, stream>>>(part, yb, T);
  // out = y @ Wo^T + bo  (f32 out)
  gemm_o<<<dim3(M / 128, C / 64), 256, 0, stream>>>(yb, wob, bo, out);
}

// Round 11
// 213.838 us; speedup vs baseline: 1.2273x; 1.1372x over previous
//
#include <hip/hip_runtime.h>

typedef unsigned short u16;
typedef unsigned int u32;
typedef __bf16 bf16x8 __attribute__((ext_vector_type(8)));
typedef unsigned short u16x8 __attribute__((ext_vector_type(8)));
typedef float f32x4 __attribute__((ext_vector_type(4)));

// XOR swizzle key for [row][64] bf16 LDS tiles (GEMM), 16B chunk granularity.
#define KEY(r) ((((r) ^ ((r) >> 3)) & 7) << 3)
// attn K/V layouts: pitch-72 rows, V^T k-swizzle keyed on d>>3 (round-3 proven)
#define GP 72
#define VKEY(d) ((((d) >> 3) & 7) << 3)

static __device__ __forceinline__ u16 f2b(float f) {
  union { float f; unsigned u; } x; x.f = f;
  unsigned r = x.u + 0x7FFFu + ((x.u >> 16) & 1u);  // RNE
  return (u16)(r >> 16);
}

static __device__ __forceinline__ bf16x8 ld_frag(const u16* p) {
  union { u16x8 s; bf16x8 b; } u;
  u.s = *reinterpret_cast<const u16x8*>(p);
  return u.b;
}

// ---------------- f32 -> bf16 convert (vectorized x4) ----------------
__global__ __launch_bounds__(256) void cvt_f32_bf16(const float* __restrict__ in,
                                                    u16* __restrict__ out, int n4) {
  int i = blockIdx.x * 256 + threadIdx.x;
  if (i >= n4) return;
  float4 v = reinterpret_cast<const float4*>(in)[i];
  ushort4 o;
  o.x = f2b(v.x); o.y = f2b(v.y); o.z = f2b(v.z); o.w = f2b(v.w);
  reinterpret_cast<ushort4*>(out)[i] = o;
}

// ---------------- GEMM body: 128xBN tile, BK=64 (unchanged) -----------------
template <bool OUT_BF16, int BN>   // BN in {64,128}
static __device__ __forceinline__ void gemm_body(
    const u16* __restrict__ A, const u16* __restrict__ Bt,
    const float* __restrict__ bias, void* __restrict__ outp,
    int N, int K, int row0, int col0, float scale) {
  constexpr int NF = BN / 32;
  __shared__ alignas(16) u16 As[128 * 64];
  __shared__ alignas(16) u16 Bs[BN * 64];
  const int tid = threadIdx.x, wid = tid >> 6, lane = tid & 63;
  const int wr = wid >> 1, wc = wid & 1;
  const int lr = lane >> 3;
  const int lc = (lane & 7) * 8;
  const int frow = lane & 15, fk = (lane >> 4) * 8;
  f32x4 acc[4][NF] = {};

  for (int k0 = 0; k0 < K; k0 += 64) {
    __syncthreads();
#pragma unroll
    for (int t = 0; t < 4; ++t) {
      const int r = wid * 32 + t * 8 + lr;
      __builtin_amdgcn_global_load_lds(
          (const __attribute__((address_space(1))) unsigned int*)(
              A + (size_t)(row0 + r) * K + k0 + (lc ^ KEY(r))),
          (__attribute__((address_space(3))) unsigned int*)(As + (wid * 32 + t * 8) * 64),
          16, 0, 0);
    }
#pragma unroll
    for (int t = 0; t < NF; ++t) {
      const int r = wid * (BN / 4) + t * 8 + lr;
      __builtin_amdgcn_global_load_lds(
          (const __attribute__((address_space(1))) unsigned int*)(
              Bt + (size_t)(col0 + r) * K + k0 + (lc ^ KEY(r))),
          (__attribute__((address_space(3))) unsigned int*)(Bs + (wid * (BN / 4) + t * 8) * 64),
          16, 0, 0);
    }
    __syncthreads();
#pragma unroll
    for (int ks = 0; ks < 2; ++ks) {
      bf16x8 a[4], b[NF];
#pragma unroll
      for (int m = 0; m < 4; ++m) {
        const int r = wr * 64 + m * 16 + frow;
        a[m] = ld_frag(&As[r * 64 + ((ks * 32 + fk) ^ KEY(r))]);
      }
#pragma unroll
      for (int n = 0; n < NF; ++n) {
        const int r = wc * (BN / 2) + n * 16 + frow;
        b[n] = ld_frag(&Bs[r * 64 + ((ks * 32 + fk) ^ KEY(r))]);
      }
#pragma unroll
      for (int m = 0; m < 4; ++m)
#pragma unroll
        for (int n = 0; n < NF; ++n)
          acc[m][n] = __builtin_amdgcn_mfma_f32_16x16x32_bf16(a[m], b[n], acc[m][n], 0, 0, 0);
    }
  }
  const int colL = lane & 15, rb = (lane >> 4) * 4;
#pragma unroll
  for (int n = 0; n < NF; ++n) {
    const int gc = col0 + wc * (BN / 2) + n * 16 + colL;
    const float bv = bias[gc];
#pragma unroll
    for (int m = 0; m < 4; ++m)
#pragma unroll
      for (int r = 0; r < 4; ++r) {
        const int gr = row0 + wr * 64 + m * 16 + rb + r;
        const float v = (acc[m][n][r] + bv) * scale;
        if constexpr (OUT_BF16)
          reinterpret_cast<u16*>(outp)[(size_t)gr * N + gc] = f2b(v);
        else
          reinterpret_cast<float*>(outp)[(size_t)gr * N + gc] = v;
      }
  }
}

__global__ __launch_bounds__(256) void gemm_qkv(
    const u16* __restrict__ xb, const u16* __restrict__ wqb,
    const u16* __restrict__ wkvb, const float* __restrict__ bq,
    const float* __restrict__ bkv, u16* __restrict__ qb, u16* __restrict__ kvb) {
  const int row0 = blockIdx.x * 128;
  const int by = blockIdx.y;
  const u16* Bt; const float* bias; u16* out; int N, col0; float scale;
  if (by < 8) { Bt = wqb;  bias = bq;  out = qb;  N = 1024; col0 = by * 128;      scale = 0.125f; }
  else        { Bt = wkvb; bias = bkv; out = kvb; N = 2048; col0 = (by - 8) * 128; scale = 1.0f; }
  gemm_body<true, 128>(xb, Bt, bias, out, N, 1024, row0, col0, scale);
}

__global__ __launch_bounds__(256) void gemm_o(
    const u16* __restrict__ yb, const u16* __restrict__ wob,
    const float* __restrict__ bo, float* __restrict__ out) {
  gemm_body<false, 64>(yb, wob, bo, out, 1024, 1024, blockIdx.x * 128, blockIdx.y * 64, 1.0f);
}

// ---------------- Flash attention: swapped QK^T + ALiBi + causal ------------
// grid (B*H, 32), qt = 31-blockIdx.y (LPT). block 256 (4 waves), wave w owns
// q rows [qBase+16w, +16). S^T = mfma(K,Q): lane owns q-column (q=lane&15),
// 16 k-values in regs -> in-register softmax (2 shfl), P packed to LDS as b64,
// read back as b128 A-frags for PV. K/V staging = round-3 proven body.
__global__ __launch_bounds__(256) void attn_kernel(
    const u16* __restrict__ qb,   // [B*T,1024] bf16, pre-scaled by 1/8
    const u16* __restrict__ kvb,  // [B*T,2048] bf16 (k: h*64, v: 1024+h*64)
    u16* __restrict__ yb,         // [B*T,1024] bf16
    int T) {
  const int C = 1024;
  const int bh = blockIdx.x;
  const int qt = (int)gridDim.y - 1 - (int)blockIdx.y;
  const int b = bh >> 4, h = bh & 15;
  const float slope = (float)(h + 1) * 0.0625f;
  const int tid = threadIdx.x, wid = tid >> 6, lane = tid & 63;
  const int qBase = qt * 64;

  __shared__ alignas(16) u16 Ks[64 * GP];     // K[k][d]
  __shared__ alignas(16) u16 Vt[64 * GP];     // V^T: Vt[d][k ^ VKEY(d)]
  __shared__ alignas(16) u32 Pl[4][16 * 40];  // per-wave P pairs, pitch 40 u32

  const int qc = lane & 15;        // q-column this lane owns (and frag row)
  const int g  = lane >> 4;        // k-subgroup 0..3
  const int g4 = g * 4;
  const int fk = g * 8;

  // Q fragments (loop-invariant): B-operand, row = qc
  const int q_row = qBase + wid * 16 + qc;
  const u16* qp = qb + (size_t)(b * T + q_row) * C + h * 64;
  const bf16x8 aq0 = ld_frag(qp + fk);
  const bf16x8 aq1 = ld_frag(qp + 32 + fk);
  const int qg = q_row;            // global q index for mask/state

  float m_q = -1e30f, l_q = 0.f;
  f32x4 accO[4] = {};

  const int sr = tid >> 3;        // 0..31
  const int sc = (tid & 7) * 8;   // 0..56

  for (int kt = 0; kt <= qt; ++kt) {
    const int kBase = kt * 64;
    __syncthreads();  // previous iteration's reads of Ks/Vt done
    {  // stage K rows + V transposed (round-3 proven)
      const size_t g0 = (size_t)(b * T + kBase + sr) * 2048 + h * 64 + sc;
      const size_t g1 = (size_t)(b * T + kBase + sr + 32) * 2048 + h * 64 + sc;
      *reinterpret_cast<int4*>(&Ks[sr * GP + sc]) = *reinterpret_cast<const int4*>(&kvb[g0]);
      *reinterpret_cast<int4*>(&Ks[(sr + 32) * GP + sc]) = *reinterpret_cast<const int4*>(&kvb[g1]);
      int4 v0 = *reinterpret_cast<const int4*>(&kvb[g0 + 1024]);
      int4 v1 = *reinterpret_cast<const int4*>(&kvb[g1 + 1024]);
      const u16* p0 = reinterpret_cast<const u16*>(&v0);
      const u16* p1 = reinterpret_cast<const u16*>(&v1);
      const int kx = VKEY(sc);
#pragma unroll
      for (int j = 0; j < 8; ++j) {
        const int d = sc + j;
        Vt[d * GP + (sr ^ kx)] = p0[j];
        Vt[d * GP + ((sr + 32) ^ kx)] = p1[j];
      }
    }
    __syncthreads();

    // S^T = K Q^T: accS[n][r] = S[k=kBase+16n+g4+r][q=qc]
    f32x4 accS[4] = {};
#pragma unroll
    for (int n = 0; n < 4; ++n) {
      bf16x8 bk0 = ld_frag(&Ks[(n * 16 + qc) * GP + fk]);
      accS[n] = __builtin_amdgcn_mfma_f32_16x16x32_bf16(bk0, aq0, accS[n], 0, 0, 0);
      bf16x8 bk1 = ld_frag(&Ks[(n * 16 + qc) * GP + 32 + fk]);
      accS[n] = __builtin_amdgcn_mfma_f32_16x16x32_bf16(bk1, aq1, accS[n], 0, 0, 0);
    }

    // in-register softmax over the lane's 16 k-values (+ ALiBi + causal)
    float tmax = -1e30f;
#pragma unroll
    for (int n = 0; n < 4; ++n) {
      const int kgn = kBase + n * 16 + g4;
#pragma unroll
      for (int r = 0; r < 4; ++r) {
        const int kg = kgn + r;
        float v = fmaf(slope, (float)kg, accS[n][r]);
        v = (kg > qg) ? -1e30f : v;
        accS[n][r] = v;
        tmax = fmaxf(tmax, v);
      }
    }
    tmax = fmaxf(tmax, __shfl_xor(tmax, 16));
    tmax = fmaxf(tmax, __shfl_xor(tmax, 32));
    const float newm = fmaxf(m_q, tmax);
    const float corr = __expf(m_q - newm);
    m_q = newm;
    float psum = 0.f;
#pragma unroll
    for (int n = 0; n < 4; ++n)
#pragma unroll
      for (int r = 0; r < 4; ++r) {
        const float p = __expf(accS[n][r] - newm);
        accS[n][r] = p;
        psum += p;
      }
    psum += __shfl_xor(psum, 16);
    psum += __shfl_xor(psum, 32);
    l_q = l_q * corr + psum;

    // pack P (bf16 truncate, P in [0,1]) -> Pl pairs; slot = 8n + 2g + p
    u32* Pw = &Pl[wid][qc * 40];
#pragma unroll
    for (int n = 0; n < 4; ++n) {
      union { float f; u32 u; } a0, a1, a2, a3;
      a0.f = accS[n][0]; a1.f = accS[n][1]; a2.f = accS[n][2]; a3.f = accS[n][3];
      u32 w0 = (a0.u >> 16) | (a1.u & 0xFFFF0000u);
      u32 w1 = (a2.u >> 16) | (a3.u & 0xFFFF0000u);
      *reinterpret_cast<uint2*>(&Pw[8 * n + 2 * g]) = uint2{w0, w1};
    }

    // rescale accO: corr for q' = g4 + r lives in lane g4+r (any g-group)
    float corr4[4];
#pragma unroll
    for (int r = 0; r < 4; ++r) corr4[r] = __shfl(corr, g4 + r);
#pragma unroll
    for (int n = 0; n < 4; ++n)
#pragma unroll
      for (int r = 0; r < 4; ++r) accO[n][r] *= corr4[r];

    // O += P @ V  (A-frag = b128 from Pl; B-frag = Vt rows)
#pragma unroll
    for (int ks = 0; ks < 2; ++ks) {
      uint4 pv4 = *reinterpret_cast<const uint4*>(&Pl[wid][qc * 40 + 16 * ks + g4]);
      union { uint4 q; u16x8 s; bf16x8 bv; } ap; ap.q = pv4;
#pragma unroll
      for (int n = 0; n < 4; ++n) {
        const int d = n * 16 + qc;
        bf16x8 bv = ld_frag(&Vt[d * GP + ((ks * 32 + fk) ^ VKEY(d))]);
        accO[n] = __builtin_amdgcn_mfma_f32_16x16x32_bf16(ap.bv, bv, accO[n], 0, 0, 0);
      }
    }
  }

  // normalize + store: accO row q' = g4 + r, col d = n*16 + qc
  float inv4[4];
#pragma unroll
  for (int r = 0; r < 4; ++r) inv4[r] = 1.0f / __shfl(l_q, g4 + r);
#pragma unroll
  for (int r = 0; r < 4; ++r) {
    const int qg2 = qBase + wid * 16 + g4 + r;
    u16* yrow = yb + (size_t)(b * T + qg2) * C + h * 64;
#pragma unroll
    for (int n = 0; n < 4; ++n) yrow[n * 16 + qc] = f2b(accO[n][r] * inv4[r]);
  }
}

extern "C" void kernel_launch(void* const* d_in, const int* in_sizes, int n_in,
                              void* d_out, int out_size, void* d_ws, size_t ws_size,
                              hipStream_t stream) {
  const float* x   = (const float*)d_in[0];
  // d_in[1] = freqs_cis (unused under ALiBi)
  const float* Wq  = (const float*)d_in[2];
  const float* bq  = (const float*)d_in[3];
  const float* Wkv = (const float*)d_in[4];
  const float* bkv = (const float*)d_in[5];
  const float* Wo  = (const float*)d_in[6];
  const float* bo  = (const float*)d_in[7];
  float* out = (float*)d_out;

  const int B = 2, T = 2048, C = 1024;
  const int M = B * T;  // 4096

  char* ws = (char*)d_ws;
  u16* xb   = (u16*)(ws + 0);          // 4096x1024  (8 MiB)
  u16* wqb  = (u16*)(ws + 8388608);    // 1024x1024  (2 MiB)
  u16* wkvb = (u16*)(ws + 10485760);   // 2048x1024  (4 MiB)
  u16* wob  = (u16*)(ws + 14680064);   // 1024x1024  (2 MiB)
  u16* qb   = (u16*)(ws + 16777216);   // 4096x1024  (8 MiB)
  u16* kvb  = (u16*)(ws + 25165824);   // 4096x2048  (16 MiB)
  u16* yb   = (u16*)(ws + 41943040);   // 4096x1024  (8 MiB)

  cvt_f32_bf16<<<(M * C / 4 + 255) / 256, 256, 0, stream>>>(x, xb, M * C / 4);
  cvt_f32_bf16<<<(C * C / 4 + 255) / 256, 256, 0, stream>>>(Wq, wqb, C * C / 4);
  cvt_f32_bf16<<<(2 * C * C / 4 + 255) / 256, 256, 0, stream>>>(Wkv, wkvb, 2 * C * C / 4);
  cvt_f32_bf16<<<(C * C / 4 + 255) / 256, 256, 0, stream>>>(Wo, wob, C * C / 4);

  // fused: q = (x@Wq^T + bq)*0.125 ; kv = x@Wkv^T + bkv
  gemm_qkv<<<dim3(M / 128, 8 + 16), 256, 0, stream>>>(xb, wqb, wkvb, bq, bkv, qb, kvb);
  // flash attention (grid: bh x qtile64, reversed for LPT balance)
  attn_kernel<<<dim3(B * 16, T / 64), 256, 0, stream>>>(qb, kvb, yb, T);
  // out = y @ Wo^T + bo  (f32 out)
  gemm_o<<<dim3(M / 128, C / 64), 256, 0, stream>>>(yb, wob, bo, out);
}